// Round 2
// baseline (250.859 us; speedup 1.0000x reference)
//
#include <hip/hip_runtime.h>
#include <stdint.h>

#define D_FEAT 64
#define NEG_INF_BITS 0xFF800000u
#define ENC_NEG_INF  0x007FFFFFu   // order-preserving encoding of -inf
#define NPB 64                      // nodes per bucket (= 1 << BSHIFT)
#define BSHIFT 6
#define BM_BLOCK 256                // bucket_max threads (4 waves -> 8 blocks/CU at the wave cap)
#define MAXB 2048                   // max buckets (N <= 131072)

// Order-preserving float->uint: enc monotone increasing with float value.
__device__ __forceinline__ unsigned enc_f32(float v) {
    unsigned b = __float_as_uint(v);
    return ((int)b >= 0) ? (b ^ 0x80000000u) : ~b;
}
__device__ __forceinline__ unsigned dec_bits(unsigned u) {
    // decoded float bits; ENC_NEG_INF maps to 0.0f
    if (u == ENC_NEG_INF) return 0u;
    return (u & 0x80000000u) ? (u ^ 0x80000000u) : ~u;
}

// ---------- K1: per-tile bucket histogram -> counts[t*B + b] (deterministic, no global atomics) ----------
__global__ void count_kernel(const int* __restrict__ dst, int* __restrict__ counts,
                             int E, int Te, int B, int aligned4) {
    __shared__ int lh[MAXB];
    for (int i = threadIdx.x; i < B; i += blockDim.x) lh[i] = 0;
    __syncthreads();
    int t = blockIdx.x;
    int beg = t * Te;
    int end = min(E, beg + Te);
    int nE = (end > beg) ? (end - beg) : 0;
    int n4 = aligned4 ? (nE >> 2) : 0;           // beg is a multiple of 4
    const int4* d4 = (const int4*)(dst + beg);
    for (int k = threadIdx.x; k < n4; k += blockDim.x) {
        int4 d = d4[k];
        atomicAdd(&lh[d.x >> BSHIFT], 1);
        atomicAdd(&lh[d.y >> BSHIFT], 1);
        atomicAdd(&lh[d.z >> BSHIFT], 1);
        atomicAdd(&lh[d.w >> BSHIFT], 1);
    }
    for (int i = beg + (n4 << 2) + threadIdx.x; i < end; i += blockDim.x)
        atomicAdd(&lh[dst[i] >> BSHIFT], 1);
    __syncthreads();
    for (int i = threadIdx.x; i < B; i += blockDim.x) counts[t * B + i] = lh[i];  // coalesced
}

// ---------- K2: column exclusive scan, one THREAD per bucket (coalesced across threads) ----------
__global__ void colscan_kernel(int* __restrict__ counts, int* __restrict__ hist,
                               int T, int B) {
    int b = blockIdx.x * blockDim.x + threadIdx.x;
    if (b >= B) return;
    int s = 0;
    int t = 0;
    for (; t + 4 <= T; t += 4) {                  // T is a multiple of 4
        int v0 = counts[(t + 0) * B + b];
        int v1 = counts[(t + 1) * B + b];
        int v2 = counts[(t + 2) * B + b];
        int v3 = counts[(t + 3) * B + b];
        counts[(t + 0) * B + b] = s; s += v0;
        counts[(t + 1) * B + b] = s; s += v1;
        counts[(t + 2) * B + b] = s; s += v2;
        counts[(t + 3) * B + b] = s; s += v3;
    }
    for (; t < T; ++t) {
        int v = counts[t * B + b];
        counts[t * B + b] = s; s += v;
    }
    hist[b] = s;
}

// ---------- K3: single-block exclusive scan of bucket totals (B <= 2048) ----------
__global__ void scan_kernel(const int* __restrict__ hist, int* __restrict__ bucket_start,
                            int B) {
    __shared__ int lds[MAXB / 2];
    int tid = threadIdx.x;
    int i0 = 2 * tid, i1 = 2 * tid + 1;
    int v0 = (i0 < B) ? hist[i0] : 0;
    int v1 = (i1 < B) ? hist[i1] : 0;
    int s = v0 + v1;
    lds[tid] = s;
    __syncthreads();
    for (int off = 1; off < (MAXB / 2); off <<= 1) {
        int t = (tid >= off) ? lds[tid - off] : 0;
        __syncthreads();
        lds[tid] += t;
        __syncthreads();
    }
    int excl = lds[tid] - s;
    if (i0 < B) bucket_start[i0] = excl;
    if (i1 < B) bucket_start[i1] = excl + v0;
    if (tid == (MAXB / 2) - 1) bucket_start[B] = lds[tid];
}

// ---------- K4: place edges (LDS cursors from precomputed offsets; no global atomics) ----------
__global__ void place_kernel(const int* __restrict__ src, const int* __restrict__ dst,
                             const int* __restrict__ counts, const int* __restrict__ bucket_start,
                             unsigned* __restrict__ packed, int E, int Te, int B) {
    __shared__ int lcur[MAXB];
    int t = blockIdx.x;
    for (int i = threadIdx.x; i < B; i += blockDim.x)
        lcur[i] = bucket_start[i] + counts[t * B + i];   // coalesced reads
    __syncthreads();
    int beg = t * Te;
    int end = min(E, beg + Te);
    for (int i = beg + threadIdx.x; i < end; i += blockDim.x) {
        int d = dst[i];
        int b = d >> BSHIFT;
        int pos = atomicAdd(&lcur[b], 1);
        packed[pos] = (unsigned)src[i] | ((unsigned)(d & (NPB - 1)) << 17);
    }
}

// ---------- K5: per-bucket scatter-max in LDS ----------
__global__ void __launch_bounds__(BM_BLOCK)
bucket_max_kernel(const float* __restrict__ h,
                  const int* __restrict__ bucket_start,
                  const unsigned* __restrict__ packed,
                  float* __restrict__ out, int N) {
    __shared__ unsigned buf[NPB * D_FEAT];   // 16 KB
    int b = blockIdx.x;
    int tid = threadIdx.x;
    int node0 = b << BSHIFT;
    int nvals = (min(NPB, N - node0)) * D_FEAT;

    for (int i = tid; i < NPB * D_FEAT; i += BM_BLOCK) buf[i] = ENC_NEG_INF;
    __syncthreads();

    int beg = bucket_start[b];
    int end = bucket_start[b + 1];
    int wid = tid >> 6;
    int lane = tid & 63;

    for (int base = beg + (wid << 6); base < end; base += BM_BLOCK) {
        int nk = min(64, end - base);
        unsigned p = (lane < nk) ? packed[base + lane] : 0u;
        int j = 0;
        for (; j + 8 <= nk; j += 8) {
            unsigned q[8];
            float v[8];
            #pragma unroll
            for (int k = 0; k < 8; ++k) q[k] = (unsigned)__shfl((int)p, j + k);
            #pragma unroll
            for (int k = 0; k < 8; ++k) v[k] = h[(q[k] & 0x1FFFFu) * D_FEAT + lane];
            #pragma unroll
            for (int k = 0; k < 8; ++k)
                atomicMax(&buf[(q[k] >> 17) * D_FEAT + lane], enc_f32(v[k]));
        }
        for (; j < nk; ++j) {
            unsigned pj = (unsigned)__shfl((int)p, j);
            float v = h[(pj & 0x1FFFFu) * D_FEAT + lane];
            atomicMax(&buf[(pj >> 17) * D_FEAT + lane], enc_f32(v));
        }
    }
    __syncthreads();

    if (nvals == NPB * D_FEAT) {
        // full bucket: vectorized decode+store
        uint4* o4 = (uint4*)(out + (size_t)node0 * D_FEAT);
        const uint4* b4 = (const uint4*)buf;
        for (int i = tid; i < (NPB * D_FEAT) / 4; i += BM_BLOCK) {
            uint4 u = b4[i];
            uint4 r;
            r.x = dec_bits(u.x); r.y = dec_bits(u.y);
            r.z = dec_bits(u.z); r.w = dec_bits(u.w);
            o4[i] = r;
        }
    } else {
        unsigned* o = (unsigned*)(out + (size_t)node0 * D_FEAT);
        for (int i = tid; i < nvals; i += BM_BLOCK) o[i] = dec_bits(buf[i]);
    }
}

// ---------- fallback: atomic scatter (large-N / tiny-ws path) ----------
__global__ void init_out_kernel(uint4* __restrict__ out, int n4) {
    int i = blockIdx.x * blockDim.x + threadIdx.x;
    if (i < n4) {
        uint4 v;
        v.x = NEG_INF_BITS; v.y = NEG_INF_BITS; v.z = NEG_INF_BITS; v.w = NEG_INF_BITS;
        out[i] = v;
    }
}
__global__ void scatter_max_kernel(const float* __restrict__ h, const int* __restrict__ src,
                                   const int* __restrict__ dst, float* __restrict__ out, int E) {
    int gid = blockIdx.x * blockDim.x + threadIdx.x;
    int e = gid >> 6;
    if (e >= E) return;
    int lane = gid & 63;
    float v = h[src[e] * D_FEAT + lane];
    int* addr = (int*)(out + dst[e] * D_FEAT + lane);
    if (v >= 0.0f) atomicMax(addr, __float_as_int(v));
    else           atomicMin((unsigned int*)addr, __float_as_uint(v));
}
__global__ void finalize_kernel(float* __restrict__ out, int n) {
    int i = blockIdx.x * blockDim.x + threadIdx.x;
    if (i < n && __float_as_uint(out[i]) == NEG_INF_BITS) out[i] = 0.0f;
}

// ---------- launch ----------
extern "C" void kernel_launch(void* const* d_in, const int* in_sizes, int n_in,
                              void* d_out, int out_size, void* d_ws, size_t ws_size,
                              hipStream_t stream) {
    const float* h = (const float*)d_in[0];
    const int* edge_index = (const int*)d_in[1];
    int E = in_sizes[1] / 2;                 // edge_index is [2, E] row-major
    const int* src = edge_index;
    const int* dst = edge_index + E;
    float* out = (float*)d_out;
    int N = out_size / D_FEAT;

    int B = (N + NPB - 1) >> BSHIFT;

    // pick the largest tile count T whose workspace fits
    int T = 0;
    for (int cand = 1024; cand >= 64; cand >>= 1) {
        size_t need = ((size_t)cand * B + B + (B + 1) + (size_t)E) * sizeof(int);
        if (ws_size >= need) { T = cand; break; }
    }

    if (N <= (1 << 17) && B <= MAXB && E > 0 && T > 0) {
        int* counts       = (int*)d_ws;                 // [T*B]
        int* hist         = counts + (size_t)T * B;     // [B]
        int* bucket_start = hist + B;                   // [B+1]
        unsigned* packed  = (unsigned*)(bucket_start + B + 1); // [E]

        int Te = ((E + T - 1) / T + 3) & ~3;            // tile size, multiple of 4
        int aligned4 = ((((uintptr_t)dst) & 15) == 0) ? 1 : 0;

        count_kernel<<<T, 256, 0, stream>>>(dst, counts, E, Te, B, aligned4);
        int cs_blocks = (B + 255) / 256;
        colscan_kernel<<<cs_blocks, 256, 0, stream>>>(counts, hist, T, B);
        scan_kernel<<<1, MAXB / 2, 0, stream>>>(hist, bucket_start, B);
        place_kernel<<<T, 256, 0, stream>>>(src, dst, counts, bucket_start, packed, E, Te, B);
        bucket_max_kernel<<<B, BM_BLOCK, 0, stream>>>(h, bucket_start, packed, out, N);
    } else {
        int n4 = out_size / 4;
        init_out_kernel<<<(n4 + 255) / 256, 256, 0, stream>>>((uint4*)out, n4);
        long long total = (long long)E * 64;
        scatter_max_kernel<<<(int)((total + 255) / 256), 256, 0, stream>>>(h, src, dst, out, E);
        finalize_kernel<<<(out_size + 255) / 256, 256, 0, stream>>>(out, out_size);
    }
}

// Round 3
// 196.545 us; speedup vs baseline: 1.2763x; 1.2763x over previous
//
#include <hip/hip_runtime.h>
#include <stdint.h>

#define D_FEAT 64
#define NEG_INF_BITS 0xFF800000u
#define ENC_NEG_INF  0x007FFFFFu   // order-preserving encoding of -inf
#define NPB 64                      // nodes per bucket (= 1 << BSHIFT)
#define BSHIFT 6
#define BM_BLOCK 256                // bucket_max threads (4 waves -> 8 blocks/CU at the wave cap)
#define MAXB 2048                   // max buckets (N <= 131072)

// Order-preserving float->uint: enc monotone increasing with float value.
__device__ __forceinline__ unsigned enc_f32(float v) {
    unsigned b = __float_as_uint(v);
    return ((int)b >= 0) ? (b ^ 0x80000000u) : ~b;
}
__device__ __forceinline__ unsigned dec_bits(unsigned u) {
    // decoded float bits; ENC_NEG_INF maps to 0.0f
    if (u == ENC_NEG_INF) return 0u;
    return (u & 0x80000000u) ? (u ^ 0x80000000u) : ~u;
}

// ---------- K1: per-tile bucket histogram -> counts[t*B + b] (deterministic, no global atomics) ----------
__global__ void count_kernel(const int* __restrict__ dst, int* __restrict__ counts,
                             int E, int Te, int B, int aligned4) {
    __shared__ int lh[MAXB];
    for (int i = threadIdx.x; i < B; i += blockDim.x) lh[i] = 0;
    __syncthreads();
    int t = blockIdx.x;
    int beg = t * Te;
    int end = min(E, beg + Te);
    int nE = (end > beg) ? (end - beg) : 0;
    int n4 = aligned4 ? (nE >> 2) : 0;           // beg is a multiple of 4
    const int4* d4 = (const int4*)(dst + beg);
    for (int k = threadIdx.x; k < n4; k += blockDim.x) {
        int4 d = d4[k];
        atomicAdd(&lh[d.x >> BSHIFT], 1);
        atomicAdd(&lh[d.y >> BSHIFT], 1);
        atomicAdd(&lh[d.z >> BSHIFT], 1);
        atomicAdd(&lh[d.w >> BSHIFT], 1);
    }
    for (int i = beg + (n4 << 2) + threadIdx.x; i < end; i += blockDim.x)
        atomicAdd(&lh[dst[i] >> BSHIFT], 1);
    __syncthreads();
    for (int i = threadIdx.x; i < B; i += blockDim.x) counts[t * B + i] = lh[i];  // coalesced
}

// ---------- K2: per-bucket column exclusive scan — one WAVE per bucket, R tiles per lane ----------
// counts[t][b] <- sum_{t'<t} counts[t'][b]; hist[b] <- column total.
template<int R>
__global__ void colscan_kernel(int* __restrict__ counts, int* __restrict__ hist,
                               int B) {
    int w = (blockIdx.x * blockDim.x + threadIdx.x) >> 6;   // wave id = bucket
    int lane = threadIdx.x & 63;
    if (w >= B) return;
    int v[R], pre[R];
    int base_t = lane * R;
    #pragma unroll
    for (int r = 0; r < R; ++r) v[r] = counts[(base_t + r) * B + w];
    int s = 0;
    #pragma unroll
    for (int r = 0; r < R; ++r) { pre[r] = s; s += v[r]; }
    int incl = s;
    #pragma unroll
    for (int off = 1; off < 64; off <<= 1) {
        int tup = __shfl_up(incl, off);
        if (lane >= off) incl += tup;
    }
    int excl = incl - s;
    #pragma unroll
    for (int r = 0; r < R; ++r) counts[(base_t + r) * B + w] = excl + pre[r];
    if (lane == 63) hist[w] = incl;
}

// ---------- K3: single-block exclusive scan of bucket totals (B <= 2048) ----------
__global__ void scan_kernel(const int* __restrict__ hist, int* __restrict__ bucket_start,
                            int B) {
    __shared__ int lds[MAXB / 2];
    int tid = threadIdx.x;
    int i0 = 2 * tid, i1 = 2 * tid + 1;
    int v0 = (i0 < B) ? hist[i0] : 0;
    int v1 = (i1 < B) ? hist[i1] : 0;
    int s = v0 + v1;
    lds[tid] = s;
    __syncthreads();
    for (int off = 1; off < (MAXB / 2); off <<= 1) {
        int t = (tid >= off) ? lds[tid - off] : 0;
        __syncthreads();
        lds[tid] += t;
        __syncthreads();
    }
    int excl = lds[tid] - s;
    if (i0 < B) bucket_start[i0] = excl;
    if (i1 < B) bucket_start[i1] = excl + v0;
    if (tid == (MAXB / 2) - 1) bucket_start[B] = lds[tid];
}

// ---------- K4: place edges (LDS cursors from precomputed offsets; no global atomics) ----------
__global__ void place_kernel(const int* __restrict__ src, const int* __restrict__ dst,
                             const int* __restrict__ counts, const int* __restrict__ bucket_start,
                             unsigned* __restrict__ packed, int E, int Te, int B) {
    __shared__ int lcur[MAXB];
    int t = blockIdx.x;
    for (int i = threadIdx.x; i < B; i += blockDim.x)
        lcur[i] = bucket_start[i] + counts[t * B + i];   // coalesced reads
    __syncthreads();
    int beg = t * Te;
    int end = min(E, beg + Te);
    for (int i = beg + threadIdx.x; i < end; i += blockDim.x) {
        int d = dst[i];
        int b = d >> BSHIFT;
        int pos = atomicAdd(&lcur[b], 1);
        packed[pos] = (unsigned)src[i] | ((unsigned)(d & (NPB - 1)) << 17);
    }
}

// ---------- K5: per-bucket scatter-max in LDS ----------
__global__ void __launch_bounds__(BM_BLOCK)
bucket_max_kernel(const float* __restrict__ h,
                  const int* __restrict__ bucket_start,
                  const unsigned* __restrict__ packed,
                  float* __restrict__ out, int N) {
    __shared__ unsigned buf[NPB * D_FEAT];   // 16 KB
    int b = blockIdx.x;
    int tid = threadIdx.x;
    int node0 = b << BSHIFT;
    int nvals = (min(NPB, N - node0)) * D_FEAT;

    for (int i = tid; i < NPB * D_FEAT; i += BM_BLOCK) buf[i] = ENC_NEG_INF;
    __syncthreads();

    int beg = bucket_start[b];
    int end = bucket_start[b + 1];
    int wid = tid >> 6;
    int lane = tid & 63;

    for (int base = beg + (wid << 6); base < end; base += BM_BLOCK) {
        int nk = min(64, end - base);
        unsigned p = (lane < nk) ? packed[base + lane] : 0u;
        int j = 0;
        for (; j + 8 <= nk; j += 8) {
            unsigned q[8];
            float v[8];
            #pragma unroll
            for (int k = 0; k < 8; ++k) q[k] = (unsigned)__shfl((int)p, j + k);
            #pragma unroll
            for (int k = 0; k < 8; ++k) v[k] = h[(q[k] & 0x1FFFFu) * D_FEAT + lane];
            #pragma unroll
            for (int k = 0; k < 8; ++k)
                atomicMax(&buf[(q[k] >> 17) * D_FEAT + lane], enc_f32(v[k]));
        }
        for (; j < nk; ++j) {
            unsigned pj = (unsigned)__shfl((int)p, j);
            float v = h[(pj & 0x1FFFFu) * D_FEAT + lane];
            atomicMax(&buf[(pj >> 17) * D_FEAT + lane], enc_f32(v));
        }
    }
    __syncthreads();

    if (nvals == NPB * D_FEAT) {
        // full bucket: vectorized decode+store
        uint4* o4 = (uint4*)(out + (size_t)node0 * D_FEAT);
        const uint4* b4 = (const uint4*)buf;
        for (int i = tid; i < (NPB * D_FEAT) / 4; i += BM_BLOCK) {
            uint4 u = b4[i];
            uint4 r;
            r.x = dec_bits(u.x); r.y = dec_bits(u.y);
            r.z = dec_bits(u.z); r.w = dec_bits(u.w);
            o4[i] = r;
        }
    } else {
        unsigned* o = (unsigned*)(out + (size_t)node0 * D_FEAT);
        for (int i = tid; i < nvals; i += BM_BLOCK) o[i] = dec_bits(buf[i]);
    }
}

// ---------- fallback: atomic scatter (large-N / tiny-ws path) ----------
__global__ void init_out_kernel(uint4* __restrict__ out, int n4) {
    int i = blockIdx.x * blockDim.x + threadIdx.x;
    if (i < n4) {
        uint4 v;
        v.x = NEG_INF_BITS; v.y = NEG_INF_BITS; v.z = NEG_INF_BITS; v.w = NEG_INF_BITS;
        out[i] = v;
    }
}
__global__ void scatter_max_kernel(const float* __restrict__ h, const int* __restrict__ src,
                                   const int* __restrict__ dst, float* __restrict__ out, int E) {
    int gid = blockIdx.x * blockDim.x + threadIdx.x;
    int e = gid >> 6;
    if (e >= E) return;
    int lane = gid & 63;
    float v = h[src[e] * D_FEAT + lane];
    int* addr = (int*)(out + dst[e] * D_FEAT + lane);
    if (v >= 0.0f) atomicMax(addr, __float_as_int(v));
    else           atomicMin((unsigned int*)addr, __float_as_uint(v));
}
__global__ void finalize_kernel(float* __restrict__ out, int n) {
    int i = blockIdx.x * blockDim.x + threadIdx.x;
    if (i < n && __float_as_uint(out[i]) == NEG_INF_BITS) out[i] = 0.0f;
}

// ---------- launch ----------
extern "C" void kernel_launch(void* const* d_in, const int* in_sizes, int n_in,
                              void* d_out, int out_size, void* d_ws, size_t ws_size,
                              hipStream_t stream) {
    const float* h = (const float*)d_in[0];
    const int* edge_index = (const int*)d_in[1];
    int E = in_sizes[1] / 2;                 // edge_index is [2, E] row-major
    const int* src = edge_index;
    const int* dst = edge_index + E;
    float* out = (float*)d_out;
    int N = out_size / D_FEAT;

    int B = (N + NPB - 1) >> BSHIFT;

    // pick the largest tile count T whose workspace fits
    int T = 0;
    for (int cand = 1024; cand >= 64; cand >>= 1) {
        size_t need = ((size_t)cand * B + B + (B + 1) + (size_t)E) * sizeof(int);
        if (ws_size >= need) { T = cand; break; }
    }

    if (N <= (1 << 17) && B <= MAXB && E > 0 && T > 0) {
        int* counts       = (int*)d_ws;                 // [T*B]
        int* hist         = counts + (size_t)T * B;     // [B]
        int* bucket_start = hist + B;                   // [B+1]
        unsigned* packed  = (unsigned*)(bucket_start + B + 1); // [E]

        int Te = ((E + T - 1) / T + 3) & ~3;            // tile size, multiple of 4
        int aligned4 = ((((uintptr_t)dst) & 15) == 0) ? 1 : 0;

        count_kernel<<<T, 256, 0, stream>>>(dst, counts, E, Te, B, aligned4);

        int cs_blocks = (B * 64 + 255) / 256;           // one wave per bucket
        switch (T >> 6) {
            case 16: colscan_kernel<16><<<cs_blocks, 256, 0, stream>>>(counts, hist, B); break;
            case  8: colscan_kernel< 8><<<cs_blocks, 256, 0, stream>>>(counts, hist, B); break;
            case  4: colscan_kernel< 4><<<cs_blocks, 256, 0, stream>>>(counts, hist, B); break;
            case  2: colscan_kernel< 2><<<cs_blocks, 256, 0, stream>>>(counts, hist, B); break;
            default: colscan_kernel< 1><<<cs_blocks, 256, 0, stream>>>(counts, hist, B); break;
        }
        scan_kernel<<<1, MAXB / 2, 0, stream>>>(hist, bucket_start, B);
        place_kernel<<<T, 256, 0, stream>>>(src, dst, counts, bucket_start, packed, E, Te, B);
        bucket_max_kernel<<<B, BM_BLOCK, 0, stream>>>(h, bucket_start, packed, out, N);
    } else {
        int n4 = out_size / 4;
        init_out_kernel<<<(n4 + 255) / 256, 256, 0, stream>>>((uint4*)out, n4);
        long long total = (long long)E * 64;
        scatter_max_kernel<<<(int)((total + 255) / 256), 256, 0, stream>>>(h, src, dst, out, E);
        finalize_kernel<<<(out_size + 255) / 256, 256, 0, stream>>>(out, out_size);
    }
}

// Round 4
// 174.904 us; speedup vs baseline: 1.4343x; 1.1237x over previous
//
#include <hip/hip_runtime.h>
#include <stdint.h>

#define D_FEAT 64
#define NEG_INF_BITS 0xFF800000u
#define ENC_NEG_INF  0x007FFFFFu   // order-preserving encoding of -inf
#define NPB 64                      // nodes per bucket (= 1 << BSHIFT)
#define BSHIFT 6
#define BM_BLOCK 320                // 5 waves -> 1563*5 = 7815 waves = 30.5/CU
#define MAXB 2048                   // max buckets (N <= 131072)

// Order-preserving float->uint: enc monotone increasing with float value.
__device__ __forceinline__ unsigned enc_f32(float v) {
    unsigned b = __float_as_uint(v);
    return ((int)b >= 0) ? (b ^ 0x80000000u) : ~b;
}
__device__ __forceinline__ unsigned dec_bits(unsigned u) {
    // decoded float bits; ENC_NEG_INF maps to 0.0f
    if (u == ENC_NEG_INF) return 0u;
    return (u & 0x80000000u) ? (u ^ 0x80000000u) : ~u;
}

// ---------- K1: per-tile bucket histogram -> counts[t*B + b] (deterministic, no global atomics) ----------
__global__ void count_kernel(const int* __restrict__ dst, int* __restrict__ counts,
                             int E, int Te, int B, int aligned4) {
    __shared__ int lh[MAXB];
    for (int i = threadIdx.x; i < B; i += blockDim.x) lh[i] = 0;
    __syncthreads();
    int t = blockIdx.x;
    int beg = t * Te;
    int end = min(E, beg + Te);
    int nE = (end > beg) ? (end - beg) : 0;
    int n4 = aligned4 ? (nE >> 2) : 0;           // beg is a multiple of 4
    const int4* d4 = (const int4*)(dst + beg);
    for (int k = threadIdx.x; k < n4; k += blockDim.x) {
        int4 d = d4[k];
        atomicAdd(&lh[d.x >> BSHIFT], 1);
        atomicAdd(&lh[d.y >> BSHIFT], 1);
        atomicAdd(&lh[d.z >> BSHIFT], 1);
        atomicAdd(&lh[d.w >> BSHIFT], 1);
    }
    for (int i = beg + (n4 << 2) + threadIdx.x; i < end; i += blockDim.x)
        atomicAdd(&lh[dst[i] >> BSHIFT], 1);
    __syncthreads();
    for (int i = threadIdx.x; i < B; i += blockDim.x) counts[t * B + i] = lh[i];  // coalesced
}

// ---------- K2: per-bucket column exclusive scan — one WAVE per bucket, R tiles per lane ----------
template<int R>
__global__ void colscan_kernel(int* __restrict__ counts, int* __restrict__ hist,
                               int B) {
    int w = (blockIdx.x * blockDim.x + threadIdx.x) >> 6;   // wave id = bucket
    int lane = threadIdx.x & 63;
    if (w >= B) return;
    int v[R], pre[R];
    int base_t = lane * R;
    #pragma unroll
    for (int r = 0; r < R; ++r) v[r] = counts[(base_t + r) * B + w];
    int s = 0;
    #pragma unroll
    for (int r = 0; r < R; ++r) { pre[r] = s; s += v[r]; }
    int incl = s;
    #pragma unroll
    for (int off = 1; off < 64; off <<= 1) {
        int tup = __shfl_up(incl, off);
        if (lane >= off) incl += tup;
    }
    int excl = incl - s;
    #pragma unroll
    for (int r = 0; r < R; ++r) counts[(base_t + r) * B + w] = excl + pre[r];
    if (lane == 63) hist[w] = incl;
}

// ---------- K3: single-block exclusive scan of bucket totals (B <= 2048) ----------
__global__ void scan_kernel(const int* __restrict__ hist, int* __restrict__ bucket_start,
                            int B) {
    __shared__ int lds[MAXB / 2];
    int tid = threadIdx.x;
    int i0 = 2 * tid, i1 = 2 * tid + 1;
    int v0 = (i0 < B) ? hist[i0] : 0;
    int v1 = (i1 < B) ? hist[i1] : 0;
    int s = v0 + v1;
    lds[tid] = s;
    __syncthreads();
    for (int off = 1; off < (MAXB / 2); off <<= 1) {
        int t = (tid >= off) ? lds[tid - off] : 0;
        __syncthreads();
        lds[tid] += t;
        __syncthreads();
    }
    int excl = lds[tid] - s;
    if (i0 < B) bucket_start[i0] = excl;
    if (i1 < B) bucket_start[i1] = excl + v0;
    if (tid == (MAXB / 2) - 1) bucket_start[B] = lds[tid];
}

// ---------- K4: place edges (LDS cursors from precomputed offsets; no global atomics) ----------
__global__ void place_kernel(const int* __restrict__ src, const int* __restrict__ dst,
                             const int* __restrict__ counts, const int* __restrict__ bucket_start,
                             unsigned* __restrict__ packed, int E, int Te, int B, int aligned4) {
    __shared__ int lcur[MAXB];
    int t = blockIdx.x;
    for (int i = threadIdx.x; i < B; i += blockDim.x)
        lcur[i] = bucket_start[i] + counts[t * B + i];   // coalesced reads
    __syncthreads();
    int beg = t * Te;
    int end = min(E, beg + Te);
    int nE = (end > beg) ? (end - beg) : 0;
    int n4 = aligned4 ? (nE >> 2) : 0;           // beg is a multiple of 4
    const int4* s4 = (const int4*)(src + beg);
    const int4* d4 = (const int4*)(dst + beg);
    for (int k = threadIdx.x; k < n4; k += blockDim.x) {
        int4 d = d4[k];
        int4 s = s4[k];
        int b0 = d.x >> BSHIFT; int p0 = atomicAdd(&lcur[b0], 1);
        packed[p0] = (unsigned)s.x | ((unsigned)(d.x & (NPB - 1)) << 17);
        int b1 = d.y >> BSHIFT; int p1 = atomicAdd(&lcur[b1], 1);
        packed[p1] = (unsigned)s.y | ((unsigned)(d.y & (NPB - 1)) << 17);
        int b2 = d.z >> BSHIFT; int p2 = atomicAdd(&lcur[b2], 1);
        packed[p2] = (unsigned)s.z | ((unsigned)(d.z & (NPB - 1)) << 17);
        int b3 = d.w >> BSHIFT; int p3 = atomicAdd(&lcur[b3], 1);
        packed[p3] = (unsigned)s.w | ((unsigned)(d.w & (NPB - 1)) << 17);
    }
    for (int i = beg + (n4 << 2) + threadIdx.x; i < end; i += blockDim.x) {
        int d = dst[i];
        int b = d >> BSHIFT;
        int pos = atomicAdd(&lcur[b], 1);
        packed[pos] = (unsigned)src[i] | ((unsigned)(d & (NPB - 1)) << 17);
    }
}

// ---------- K5: per-bucket scatter-max in LDS (float2 gather, 2 edges per load) ----------
__global__ void __launch_bounds__(BM_BLOCK, 8)
bucket_max_kernel(const float* __restrict__ h,
                  const int* __restrict__ bucket_start,
                  const unsigned* __restrict__ packed,
                  float* __restrict__ out, int N) {
    __shared__ unsigned buf[NPB * D_FEAT];   // 16 KB
    int b = blockIdx.x;
    int tid = threadIdx.x;
    int node0 = b << BSHIFT;
    int nvals = (min(NPB, N - node0)) * D_FEAT;

    for (int i = tid; i < NPB * D_FEAT; i += BM_BLOCK) buf[i] = ENC_NEG_INF;
    __syncthreads();

    int beg = bucket_start[b];
    int end = bucket_start[b + 1];
    int wid = tid >> 6;          // 0..4
    int lane = tid & 63;
    int sub2 = lane >> 5;        // which edge of the pair this lane serves (0/1)
    int fo2 = (lane & 31) << 1;  // feature dword offset (0,2,...,62)

    for (int base = beg + (wid << 6); base < end; base += BM_BLOCK / 64 * 64) {
        int nk = min(64, end - base);
        unsigned p = (lane < nk) ? packed[base + lane] : 0u;
        int j = 0;
        // vector path: 16 edges per iter, 8 float2 loads (4 KB in flight per wave)
        for (; j + 16 <= nk; j += 16) {
            unsigned q[8];
            #pragma unroll
            for (int k = 0; k < 8; ++k)
                q[k] = (unsigned)__shfl((int)p, j + 2 * k + sub2);
            float2 v[8];
            #pragma unroll
            for (int k = 0; k < 8; ++k)
                v[k] = *(const float2*)&h[(size_t)(q[k] & 0x1FFFFu) * D_FEAT + fo2];
            #pragma unroll
            for (int k = 0; k < 8; ++k) {
                unsigned nb = (q[k] >> 17) * D_FEAT + fo2;
                // c=0: lo half writes comp0 at +0, hi half comp1 at +1 (disjoint banks)
                float a0 = sub2 ? v[k].y : v[k].x;
                atomicMax(&buf[nb + sub2], enc_f32(a0));
                // c=1: complementary component at complementary slot
                float a1 = sub2 ? v[k].x : v[k].y;
                atomicMax(&buf[nb + (1 - sub2)], enc_f32(a1));
            }
        }
        // scalar tail: one edge at a time, lane = feature
        for (; j < nk; ++j) {
            unsigned pj = (unsigned)__shfl((int)p, j);
            float v = h[(size_t)(pj & 0x1FFFFu) * D_FEAT + lane];
            atomicMax(&buf[(pj >> 17) * D_FEAT + lane], enc_f32(v));
        }
    }
    __syncthreads();

    if (nvals == NPB * D_FEAT) {
        uint4* o4 = (uint4*)(out + (size_t)node0 * D_FEAT);
        const uint4* b4 = (const uint4*)buf;
        for (int i = tid; i < (NPB * D_FEAT) / 4; i += BM_BLOCK) {
            uint4 u = b4[i];
            uint4 r;
            r.x = dec_bits(u.x); r.y = dec_bits(u.y);
            r.z = dec_bits(u.z); r.w = dec_bits(u.w);
            o4[i] = r;
        }
    } else {
        unsigned* o = (unsigned*)(out + (size_t)node0 * D_FEAT);
        for (int i = tid; i < nvals; i += BM_BLOCK) o[i] = dec_bits(buf[i]);
    }
}

// ---------- fallback: atomic scatter (large-N / tiny-ws path) ----------
__global__ void init_out_kernel(uint4* __restrict__ out, int n4) {
    int i = blockIdx.x * blockDim.x + threadIdx.x;
    if (i < n4) {
        uint4 v;
        v.x = NEG_INF_BITS; v.y = NEG_INF_BITS; v.z = NEG_INF_BITS; v.w = NEG_INF_BITS;
        out[i] = v;
    }
}
__global__ void scatter_max_kernel(const float* __restrict__ h, const int* __restrict__ src,
                                   const int* __restrict__ dst, float* __restrict__ out, int E) {
    int gid = blockIdx.x * blockDim.x + threadIdx.x;
    int e = gid >> 6;
    if (e >= E) return;
    int lane = gid & 63;
    float v = h[src[e] * D_FEAT + lane];
    int* addr = (int*)(out + dst[e] * D_FEAT + lane);
    if (v >= 0.0f) atomicMax(addr, __float_as_int(v));
    else           atomicMin((unsigned int*)addr, __float_as_uint(v));
}
__global__ void finalize_kernel(float* __restrict__ out, int n) {
    int i = blockIdx.x * blockDim.x + threadIdx.x;
    if (i < n && __float_as_uint(out[i]) == NEG_INF_BITS) out[i] = 0.0f;
}

// ---------- launch ----------
extern "C" void kernel_launch(void* const* d_in, const int* in_sizes, int n_in,
                              void* d_out, int out_size, void* d_ws, size_t ws_size,
                              hipStream_t stream) {
    const float* h = (const float*)d_in[0];
    const int* edge_index = (const int*)d_in[1];
    int E = in_sizes[1] / 2;                 // edge_index is [2, E] row-major
    const int* src = edge_index;
    const int* dst = edge_index + E;
    float* out = (float*)d_out;
    int N = out_size / D_FEAT;

    int B = (N + NPB - 1) >> BSHIFT;

    // pick the largest tile count T whose workspace fits (T=512 preferred: 2 blocks/CU)
    int T = 0;
    for (int cand = 512; cand >= 64; cand >>= 1) {
        size_t need = ((size_t)cand * B + B + (B + 1) + (size_t)E) * sizeof(int);
        if (ws_size >= need) { T = cand; break; }
    }

    if (N <= (1 << 17) && B <= MAXB && E > 0 && T > 0) {
        int* counts       = (int*)d_ws;                 // [T*B]
        int* hist         = counts + (size_t)T * B;     // [B]
        int* bucket_start = hist + B;                   // [B+1]
        unsigned* packed  = (unsigned*)(bucket_start + B + 1); // [E]

        int Te = ((E + T - 1) / T + 3) & ~3;            // tile size, multiple of 4
        int aligned4 = (((((uintptr_t)dst) | ((uintptr_t)src)) & 15) == 0) ? 1 : 0;

        count_kernel<<<T, 512, 0, stream>>>(dst, counts, E, Te, B, aligned4);

        int cs_blocks = (B * 64 + 255) / 256;           // one wave per bucket
        switch (T >> 6) {
            case  8: colscan_kernel< 8><<<cs_blocks, 256, 0, stream>>>(counts, hist, B); break;
            case  4: colscan_kernel< 4><<<cs_blocks, 256, 0, stream>>>(counts, hist, B); break;
            case  2: colscan_kernel< 2><<<cs_blocks, 256, 0, stream>>>(counts, hist, B); break;
            default: colscan_kernel< 1><<<cs_blocks, 256, 0, stream>>>(counts, hist, B); break;
        }
        scan_kernel<<<1, MAXB / 2, 0, stream>>>(hist, bucket_start, B);
        place_kernel<<<T, 512, 0, stream>>>(src, dst, counts, bucket_start, packed, E, Te, B, aligned4);
        bucket_max_kernel<<<B, BM_BLOCK, 0, stream>>>(h, bucket_start, packed, out, N);
    } else {
        int n4 = out_size / 4;
        init_out_kernel<<<(n4 + 255) / 256, 256, 0, stream>>>((uint4*)out, n4);
        long long total = (long long)E * 64;
        scatter_max_kernel<<<(int)((total + 255) / 256), 256, 0, stream>>>(h, src, dst, out, E);
        finalize_kernel<<<(out_size + 255) / 256, 256, 0, stream>>>(out, out_size);
    }
}